// Round 1
// baseline (1190.861 us; speedup 1.0000x reference)
//
#include <hip/hip_runtime.h>
#include <math.h>

// Problem constants
#define NB 2          // batch
#define DM_ 128       // model dim
#define LL 4096       // sequence length (64*64)
#define DI_ 256       // inner dim
#define DTRN 8        // dt rank
#define DSN 16        // state dim
#define RR 40         // DTR + 2*DS
#define NCH 32        // scan chunks
#define CHL 128       // chunk length
#define EPSF 1e-5f

// workspace layout (float offsets)
#define O_XZ   ((size_t)0)          // F*B*512*L          = 8388608
#define O_DBL  ((size_t)8388608)    // F*3*B*L*40         = 1966080
#define O_DT   ((size_t)10354688)   // F*3*B*256*L        = 12582912
#define O_P    ((size_t)22937600)   // F*3*B*256*32*16    = 1572864
#define O_S    ((size_t)24510464)   // 1572864
#define O_H    ((size_t)26083328)   // 1572864
#define O_YS   ((size_t)27656192)   // F*B*256*L          = 4194304
#define O_FT   ((size_t)31850496)   // F*B*128*L          = 2097152
#define O_DP   ((size_t)33947648)   // B*128*128          = 32768
#define O_RT   ((size_t)33980416)   // B*L*128            = 1048576
#define O_ST   ((size_t)35028992)   // 256
#define O_XC   ((size_t)35029248)   // F*3*B*256*L        = 12582912
#define NEED_BASE ((size_t)35029248 * 4)
#define NEED_XC   ((size_t)47612160 * 4)

__device__ __forceinline__ int perm_idx(int dir, int t) {
    if (dir == 0) return t;
    if (dir == 1) return (LL - 1) - t;
    return ((t & 63) << 6) | (t >> 6);   // 64x64 transpose, self-inverse
}
__device__ __forceinline__ float softplusf(float x) {
    return fmaxf(x, 0.0f) + log1pf(expf(-fabsf(x)));
}
__device__ __forceinline__ float siluf(float x) {
    return x / (1.0f + expf(-x));
}

// ---------------------------------------------------------------------------
// K1: layernorm over channels + in_proj (xn @ Win^T), write xz[f][b][j][l]
// one block per (f, b, 8 l-positions)
__global__ __launch_bounds__(256) void k1_ln_inproj(
    const float* __restrict__ x1, const float* __restrict__ x2,
    const float* __restrict__ ln_g, const float* __restrict__ ln_b,
    const float* __restrict__ Win, float* __restrict__ xz)
{
    __shared__ float xs[DM_ * 8];
    __shared__ float red1[64], red2[64];
    __shared__ float muS[8], rsS[8];
    int gid = blockIdx.x;
    int tile = gid & 511; int b = (gid >> 9) & 1; int f = gid >> 10;
    int l0 = tile * 8;
    const float* X = (f == 0 ? x1 : x2) + (size_t)b * DM_ * LL;
    int tid = threadIdx.x;
    for (int idx = tid; idx < DM_ * 8; idx += 256) {
        int c = idx >> 3, i = idx & 7;
        xs[idx] = X[(size_t)c * LL + l0 + i];
    }
    __syncthreads();
    if (tid < 64) {
        int i = tid & 7, part = tid >> 3;
        float s1 = 0.f, s2 = 0.f;
        for (int c = part * 16; c < part * 16 + 16; ++c) {
            float v = xs[c * 8 + i];
            s1 += v; s2 += v * v;
        }
        red1[tid] = s1; red2[tid] = s2;
    }
    __syncthreads();
    if (tid < 8) {
        float s1 = 0.f, s2 = 0.f;
        for (int p = 0; p < 8; ++p) { s1 += red1[p * 8 + tid]; s2 += red2[p * 8 + tid]; }
        float mu = s1 * (1.0f / 128.0f);
        float var = s2 * (1.0f / 128.0f) - mu * mu;
        muS[tid] = mu; rsS[tid] = rsqrtf(var + EPSF);
    }
    __syncthreads();
    for (int idx = tid; idx < DM_ * 8; idx += 256) {
        int c = idx >> 3, i = idx & 7;
        xs[idx] = (xs[idx] - muS[i]) * rsS[i] * ln_g[c] + ln_b[c];
    }
    __syncthreads();
    int j = tid;
    float acc0[8], acc1[8];
    #pragma unroll
    for (int i = 0; i < 8; ++i) { acc0[i] = 0.f; acc1[i] = 0.f; }
    const float* w0p = Win + (size_t)j * DM_;
    const float* w1p = Win + (size_t)(j + 256) * DM_;
    for (int c = 0; c < DM_; ++c) {
        float w0 = w0p[c], w1 = w1p[c];
        #pragma unroll
        for (int i = 0; i < 8; ++i) {
            float v = xs[c * 8 + i];
            acc0[i] += w0 * v; acc1[i] += w1 * v;
        }
    }
    float* o0 = xz + ((size_t)(f * 2 + b) * 512 + j) * LL + l0;
    float* o1 = xz + ((size_t)(f * 2 + b) * 512 + j + 256) * LL + l0;
    #pragma unroll
    for (int i = 0; i < 8; ++i) { o0[i] = acc0[i]; o1[i] = acc1[i]; }
}

// ---------------------------------------------------------------------------
// K2: causal conv(4)+silu, xproj (-> dbl), dt = softplus(dbl[:8]@dpw^T + dpb)
// one block per (f, dir, b, 32 t-positions)
__global__ __launch_bounds__(256) void k2_conv_xproj_dt(
    const float* __restrict__ xz, const float* __restrict__ conv_w,
    const float* __restrict__ conv_b, const float* __restrict__ xproj_w,
    const float* __restrict__ dtproj_w, const float* __restrict__ dtproj_b,
    float* __restrict__ dbl_g, float* __restrict__ dt_g,
    float* __restrict__ xc_g, int use_xc)
{
    __shared__ float xcs[DI_ * 33];
    __shared__ float dbls[RR * 33];
    int gid = blockIdx.x;
    int tile = gid & 127; gid >>= 7;
    int b = gid & 1; gid >>= 1;
    int dir = gid % 3, f = gid / 3;
    int t0 = tile * 32;
    int d = threadIdx.x;
    int sd = (f * 3 + dir) * 2 + b;
    const float* xrow = xz + ((size_t)(f * 2 + b) * 512 + d) * LL;
    float w0 = conv_w[(dir * DI_ + d) * 4 + 0];
    float w1 = conv_w[(dir * DI_ + d) * 4 + 1];
    float w2 = conv_w[(dir * DI_ + d) * 4 + 2];
    float w3 = conv_w[(dir * DI_ + d) * 4 + 3];
    float cb = conv_b[dir * DI_ + d];
    float r0 = (t0 >= 3) ? xrow[perm_idx(dir, t0 - 3)] : 0.f;
    float r1 = (t0 >= 2) ? xrow[perm_idx(dir, t0 - 2)] : 0.f;
    float r2 = (t0 >= 1) ? xrow[perm_idx(dir, t0 - 1)] : 0.f;
    for (int tt = 0; tt < 32; ++tt) {
        float r3 = xrow[perm_idx(dir, t0 + tt)];
        float v = cb + w0 * r0 + w1 * r1 + w2 * r2 + w3 * r3;
        xcs[d * 33 + tt] = siluf(v);
        r0 = r1; r1 = r2; r2 = r3;
    }
    __syncthreads();
    if (use_xc) {
        float* xcrow = xc_g + ((size_t)sd * DI_ + d) * LL + t0;
        for (int tt = 0; tt < 32; ++tt) xcrow[tt] = xcs[d * 33 + tt];
    }
    const float* xpw = xproj_w + (size_t)dir * RR * DI_;
    float* dblrow = dbl_g + ((size_t)sd * LL + t0) * RR;
    for (int k = 0; k < 5; ++k) {
        int idx = threadIdx.x + k * 256;
        int r = idx >> 5, tt = idx & 31;
        const float* wr = xpw + (size_t)r * DI_;
        float acc = 0.f;
        for (int dd = 0; dd < DI_; ++dd) acc += xcs[dd * 33 + tt] * wr[dd];
        dbls[r * 33 + tt] = acc;
        dblrow[tt * RR + r] = acc;
    }
    __syncthreads();
    float pw[DTRN];
    #pragma unroll
    for (int r = 0; r < DTRN; ++r) pw[r] = dtproj_w[(dir * DI_ + d) * DTRN + r];
    float bias = dtproj_b[dir * DI_ + d];
    float* dtrow = dt_g + ((size_t)sd * DI_ + d) * LL + t0;
    for (int tt = 0; tt < 32; ++tt) {
        float acc = bias;
        #pragma unroll
        for (int r = 0; r < DTRN; ++r) acc += pw[r] * dbls[r * 33 + tt];
        dtrow[tt] = softplusf(acc);
    }
}

// ---------------------------------------------------------------------------
// K3: scan pass 1 — per chunk compute P = prod(a), S = local state (h0=0)
// block = 16 subscans (16 lanes each): (f, dir, b, chunk, 16 consecutive d)
__global__ __launch_bounds__(256) void k3_pass1(
    const float* __restrict__ xz, const float* __restrict__ dbl_g,
    const float* __restrict__ dt_g, const float* __restrict__ conv_w,
    const float* __restrict__ conv_b, const float* __restrict__ A_log,
    const float* __restrict__ xc_g, int use_xc,
    float* __restrict__ Pb, float* __restrict__ Sb)
{
    int gid = blockIdx.x;
    int dgrp = gid & 15; gid >>= 4;
    int chunk = gid & 31; gid >>= 5;
    int b = gid & 1; gid >>= 1;
    int dir = gid % 3, f = gid / 3;
    int tid = threadIdx.x;
    int d = dgrp * 16 + (tid >> 4);
    int n = tid & 15;
    int t0 = chunk * CHL;
    int sd = (f * 3 + dir) * 2 + b;
    float An = -expf(A_log[(dir * DI_ + d) * DSN + n]);
    const float* dtrow = dt_g + ((size_t)sd * DI_ + d) * LL;
    const float* dblb = dbl_g + (size_t)sd * LL * RR;
    float P = 1.0f, S = 0.0f;
    if (use_xc) {
        const float* xcrow = xc_g + ((size_t)sd * DI_ + d) * LL;
        for (int s = 0; s < CHL; ++s) {
            int t = t0 + s;
            float dtv = dtrow[t];
            float xv = xcrow[t];
            float Bn = dblb[(size_t)t * RR + DTRN + n];
            float a = expf(dtv * An);
            P *= a;
            S = fmaf(S, a, dtv * xv * Bn);
        }
    } else {
        const float* xrow = xz + ((size_t)(f * 2 + b) * 512 + d) * LL;
        float w0 = conv_w[(dir * DI_ + d) * 4 + 0];
        float w1 = conv_w[(dir * DI_ + d) * 4 + 1];
        float w2 = conv_w[(dir * DI_ + d) * 4 + 2];
        float w3 = conv_w[(dir * DI_ + d) * 4 + 3];
        float cb = conv_b[dir * DI_ + d];
        float r0 = (t0 >= 3) ? xrow[perm_idx(dir, t0 - 3)] : 0.f;
        float r1 = (t0 >= 2) ? xrow[perm_idx(dir, t0 - 2)] : 0.f;
        float r2 = (t0 >= 1) ? xrow[perm_idx(dir, t0 - 1)] : 0.f;
        for (int s = 0; s < CHL; ++s) {
            int t = t0 + s;
            float r3 = xrow[perm_idx(dir, t)];
            float xc = cb + w0 * r0 + w1 * r1 + w2 * r2 + w3 * r3;
            r0 = r1; r1 = r2; r2 = r3;
            float xv = siluf(xc);
            float dtv = dtrow[t];
            float Bn = dblb[(size_t)t * RR + DTRN + n];
            float a = expf(dtv * An);
            P *= a;
            S = fmaf(S, a, dtv * xv * Bn);
        }
    }
    size_t psi = (((size_t)sd * DI_ + d) * NCH + chunk) * DSN + n;
    Pb[psi] = P;
    Sb[psi] = S;
}

// ---------------------------------------------------------------------------
// K4: propagate chunk-boundary states sequentially across 32 chunks
__global__ __launch_bounds__(256) void k4_combine(
    const float* __restrict__ Pb, const float* __restrict__ Sb,
    float* __restrict__ Hb)
{
    int id = blockIdx.x * 256 + threadIdx.x;   // 49152 total
    size_t base = (size_t)(id >> 4) * (NCH * DSN) + (id & 15);
    float h = 0.f;
    for (int c = 0; c < NCH; ++c) {
        size_t idx = base + (size_t)c * DSN;
        Hb[idx] = h;
        h = Pb[idx] * h + Sb[idx];
    }
}

// ---------------------------------------------------------------------------
// K5: scan pass 3 — rerun chunks with h0, emit y*silu(z) -> atomicAdd ysum
__global__ __launch_bounds__(256) void k5_pass3(
    const float* __restrict__ xz, const float* __restrict__ dbl_g,
    const float* __restrict__ dt_g, const float* __restrict__ conv_w,
    const float* __restrict__ conv_b, const float* __restrict__ A_log,
    const float* __restrict__ Dvec, const float* __restrict__ Hb,
    const float* __restrict__ xc_g, int use_xc,
    float* __restrict__ ysum)
{
    int gid = blockIdx.x;
    int dgrp = gid & 15; gid >>= 4;
    int chunk = gid & 31; gid >>= 5;
    int b = gid & 1; gid >>= 1;
    int dir = gid % 3, f = gid / 3;
    int tid = threadIdx.x;
    int d = dgrp * 16 + (tid >> 4);
    int n = tid & 15;
    int t0 = chunk * CHL;
    int sd = (f * 3 + dir) * 2 + b;
    float An = -expf(A_log[(dir * DI_ + d) * DSN + n]);
    float Dd = Dvec[dir * DI_ + d];
    const float* dtrow = dt_g + ((size_t)sd * DI_ + d) * LL;
    const float* dblb = dbl_g + (size_t)sd * LL * RR;
    const float* zrow = xz + ((size_t)(f * 2 + b) * 512 + DI_ + d) * LL;
    float* yrow = ysum + ((size_t)(f * 2 + b) * DI_ + d) * LL;
    size_t psi = (((size_t)sd * DI_ + d) * NCH + chunk) * DSN + n;
    float h = Hb[psi];

    const float* xcrow = xc_g + ((size_t)sd * DI_ + d) * LL;
    const float* xrow = xz + ((size_t)(f * 2 + b) * 512 + d) * LL;
    float w0 = conv_w[(dir * DI_ + d) * 4 + 0];
    float w1 = conv_w[(dir * DI_ + d) * 4 + 1];
    float w2 = conv_w[(dir * DI_ + d) * 4 + 2];
    float w3 = conv_w[(dir * DI_ + d) * 4 + 3];
    float cb = conv_b[dir * DI_ + d];
    float r0 = 0.f, r1 = 0.f, r2 = 0.f;
    if (!use_xc) {
        r0 = (t0 >= 3) ? xrow[perm_idx(dir, t0 - 3)] : 0.f;
        r1 = (t0 >= 2) ? xrow[perm_idx(dir, t0 - 2)] : 0.f;
        r2 = (t0 >= 1) ? xrow[perm_idx(dir, t0 - 1)] : 0.f;
    }
    for (int s = 0; s < CHL; ++s) {
        int t = t0 + s;
        float xv;
        if (use_xc) {
            xv = xcrow[t];
        } else {
            float r3 = xrow[perm_idx(dir, t)];
            float xc = cb + w0 * r0 + w1 * r1 + w2 * r2 + w3 * r3;
            r0 = r1; r1 = r2; r2 = r3;
            xv = siluf(xc);
        }
        float dtv = dtrow[t];
        float Bn = dblb[(size_t)t * RR + DTRN + n];
        float Cn = dblb[(size_t)t * RR + DTRN + DSN + n];
        float a = expf(dtv * An);
        h = fmaf(h, a, dtv * xv * Bn);
        float r = h * Cn;
        r += __shfl_xor(r, 1);
        r += __shfl_xor(r, 2);
        r += __shfl_xor(r, 4);
        r += __shfl_xor(r, 8);
        if (n == 0) {
            int lp = perm_idx(dir, t);
            float y = r + Dd * xv;
            float z = zrow[lp];
            atomicAdd(&yrow[lp], y * siluf(z));
        }
    }
}

// ---------------------------------------------------------------------------
// K6: out_proj: feat[f][b][c][l] = sum_d ysum[f][b][d][l] * Wout[c][d]
__global__ __launch_bounds__(256) void k6_outproj(
    const float* __restrict__ ysum, const float* __restrict__ Wout,
    float* __restrict__ feat)
{
    int gid = blockIdx.x;
    int lt = gid & 15; int cg = (gid >> 4) & 15; int b = (gid >> 8) & 1; int f = gid >> 9;
    int l = lt * 256 + threadIdx.x;
    const float* ybase = ysum + ((size_t)(f * 2 + b) * DI_) * LL + l;
    int c0 = cg * 8;
    float acc[8];
    #pragma unroll
    for (int k = 0; k < 8; ++k) acc[k] = 0.f;
    for (int dd = 0; dd < DI_; ++dd) {
        float v = ybase[(size_t)dd * LL];
        #pragma unroll
        for (int k = 0; k < 8; ++k) acc[k] += v * Wout[(c0 + k) * DI_ + dd];
    }
    #pragma unroll
    for (int k = 0; k < 8; ++k)
        feat[((size_t)(f * 2 + b) * DM_ + c0 + k) * LL + l] = acc[k];
}

// ---------------------------------------------------------------------------
// K7a: dp[b][c][d] = sum_l featA[b][c][l]*featB[b][d][l] (l-chunked atomics)
__global__ __launch_bounds__(256) void k7a_dp(
    const float* __restrict__ feat, float* __restrict__ dp)
{
    __shared__ float As[16 * 132];
    __shared__ float Bs[16 * 132];
    int gid = blockIdx.x;
    int lc = gid & 7; int dg = (gid >> 3) & 7; int cg = (gid >> 6) & 7; int b = (gid >> 9) & 1;
    int tid = threadIdx.x;
    int cc = tid & 15, dd = tid >> 4;
    int c0 = cg * 16, d0 = dg * 16, l0 = lc * 512;
    const float* fa = feat + ((size_t)(0 * 2 + b) * DM_) * LL;
    const float* fb = feat + ((size_t)(1 * 2 + b) * DM_) * LL;
    float acc = 0.f;
    for (int st = 0; st < 4; ++st) {
        __syncthreads();
        #pragma unroll
        for (int k = 0; k < 8; ++k) {
            int idx = tid + k * 256;
            int c = idx >> 7, ll = idx & 127;
            As[c * 132 + ll] = fa[(size_t)(c0 + c) * LL + l0 + st * 128 + ll];
            Bs[c * 132 + ll] = fb[(size_t)(d0 + c) * LL + l0 + st * 128 + ll];
        }
        __syncthreads();
        for (int ll = 0; ll < 128; ++ll)
            acc += As[cc * 132 + ll] * Bs[dd * 132 + ll];
    }
    atomicAdd(&dp[((size_t)b * DM_ + c0 + cc) * DM_ + d0 + dd], acc);
}

// ---------------------------------------------------------------------------
// K7b: res_t[b][l][c] = sum_d dp[b][c][d]*featB[b][d][l]; + BN channel stats
// block = (b, 32 l) -> exactly one BN channel c' = l>>5
__global__ __launch_bounds__(256) void k7b_res(
    const float* __restrict__ feat, const float* __restrict__ dp,
    float* __restrict__ res_t, float* __restrict__ stats)
{
    __shared__ float fBs[DM_ * 33];
    __shared__ float red[256];
    int gid = blockIdx.x;
    int ltile = gid & 127; int b = gid >> 7;
    int l0 = ltile * 32;
    int tid = threadIdx.x;
    const float* fb = feat + ((size_t)(2 + b) * DM_) * LL;
    for (int idx = tid; idx < DM_ * 32; idx += 256) {
        int d = idx >> 5, ll = idx & 31;
        fBs[d * 33 + ll] = fb[(size_t)d * LL + l0 + ll];
    }
    __syncthreads();
    int ll = tid & 31, cg = tid >> 5;
    const float* dpb = dp + (size_t)b * DM_ * DM_;
    float acc[16];
    #pragma unroll
    for (int k = 0; k < 16; ++k) acc[k] = 0.f;
    for (int d = 0; d < DM_; ++d) {
        float v = fBs[d * 33 + ll];
        #pragma unroll
        for (int k = 0; k < 16; ++k)
            acc[k] += dpb[(size_t)(cg * 16 + k) * DM_ + d] * v;
    }
    float s1 = 0.f, s2 = 0.f;
    float* out = res_t + ((size_t)b * LL + l0 + ll) * DM_ + cg * 16;
    #pragma unroll
    for (int k = 0; k < 16; ++k) {
        out[k] = acc[k];
        s1 += acc[k]; s2 += acc[k] * acc[k];
    }
    red[tid] = s1; __syncthreads();
    for (int s = 128; s > 0; s >>= 1) { if (tid < s) red[tid] += red[tid + s]; __syncthreads(); }
    if (tid == 0) atomicAdd(&stats[ltile], red[0]);
    __syncthreads();
    red[tid] = s2; __syncthreads();
    for (int s = 128; s > 0; s >>= 1) { if (tid < s) red[tid] += red[tid + s]; __syncthreads(); }
    if (tid == 0) atomicAdd(&stats[DM_ + ltile], red[0]);
}

// ---------------------------------------------------------------------------
// K7d: batchnorm finalize; res_t flat index == output flat index
__global__ __launch_bounds__(256) void k7d_bn(
    const float* __restrict__ res_t, const float* __restrict__ stats,
    const float* __restrict__ bn_g, const float* __restrict__ bn_b,
    float* __restrict__ outp)
{
    int i = blockIdx.x * 256 + threadIdx.x;   // 1048576 total
    int m = i & (524288 - 1);
    int cp = m >> 12;
    float mu = stats[cp] * (1.0f / 8192.0f);
    float var = stats[DM_ + cp] * (1.0f / 8192.0f) - mu * mu;
    float v = res_t[i];
    outp[i] = (v - mu) * rsqrtf(var + EPSF) * bn_g[cp] + bn_b[cp];
}

// ---------------------------------------------------------------------------
extern "C" void kernel_launch(void* const* d_in, const int* in_sizes, int n_in,
                              void* d_out, int out_size, void* d_ws, size_t ws_size,
                              hipStream_t stream)
{
    (void)in_sizes; (void)n_in; (void)out_size;
    const float* x1   = (const float*)d_in[0];
    const float* x2   = (const float*)d_in[1];
    const float* ln_g = (const float*)d_in[2];
    const float* ln_b = (const float*)d_in[3];
    const float* Win  = (const float*)d_in[4];
    const float* cw   = (const float*)d_in[5];
    const float* cb   = (const float*)d_in[6];
    const float* xpw  = (const float*)d_in[7];
    const float* dpw  = (const float*)d_in[8];
    const float* dpb  = (const float*)d_in[9];
    const float* Alog = (const float*)d_in[10];
    const float* Dv   = (const float*)d_in[11];
    const float* Wout = (const float*)d_in[12];
    const float* bn_g = (const float*)d_in[13];
    const float* bn_b = (const float*)d_in[14];
    float* outp = (float*)d_out;
    float* ws = (float*)d_ws;

    float* xz   = ws + O_XZ;
    float* dblg = ws + O_DBL;
    float* dtg  = ws + O_DT;
    float* Pb   = ws + O_P;
    float* Sb   = ws + O_S;
    float* Hb   = ws + O_H;
    float* ysum = ws + O_YS;
    float* feat = ws + O_FT;
    float* dpB  = ws + O_DP;
    float* rest = ws + O_RT;
    float* stat = ws + O_ST;
    float* xcg  = ws + O_XC;
    int use_xc = (ws_size >= NEED_XC) ? 1 : 0;

    hipMemsetAsync(ysum, 0, (size_t)4194304 * 4, stream);
    hipMemsetAsync(dpB, 0, (size_t)32768 * 4, stream);
    hipMemsetAsync(stat, 0, (size_t)256 * 4, stream);

    k1_ln_inproj<<<2048, 256, 0, stream>>>(x1, x2, ln_g, ln_b, Win, xz);
    k2_conv_xproj_dt<<<1536, 256, 0, stream>>>(xz, cw, cb, xpw, dpw, dpb,
                                               dblg, dtg, xcg, use_xc);
    k3_pass1<<<6144, 256, 0, stream>>>(xz, dblg, dtg, cw, cb, Alog,
                                       xcg, use_xc, Pb, Sb);
    k4_combine<<<192, 256, 0, stream>>>(Pb, Sb, Hb);
    k5_pass3<<<6144, 256, 0, stream>>>(xz, dblg, dtg, cw, cb, Alog, Dv, Hb,
                                       xcg, use_xc, ysum);
    k6_outproj<<<1024, 256, 0, stream>>>(ysum, Wout, feat);
    k7a_dp<<<1024, 256, 0, stream>>>(feat, dpB);
    k7b_res<<<256, 256, 0, stream>>>(feat, dpB, rest, stat);
    k7d_bn<<<4096, 256, 0, stream>>>(rest, stat, bn_g, bn_b, outp);
}

// Round 2
// 623.945 us; speedup vs baseline: 1.9086x; 1.9086x over previous
//
#include <hip/hip_runtime.h>
#include <math.h>

// Problem constants
#define DM_ 128       // model dim
#define LL 4096       // sequence length (64*64)
#define DI_ 256       // inner dim
#define DTRN 8        // dt rank
#define DSN 16        // state dim
#define RR 40         // DTR + 2*DS
#define NCH 64        // scan chunks
#define CHL 64        // chunk length
#define EPSF 1e-5f

// workspace layout (float offsets), total ~27.2M floats = 109 MB
#define O_XT   ((size_t)0)           // fb x L x 256       = 4,194,304
#define O_ZT   ((size_t)4194304)     // fb x L x 256       = 4,194,304
#define O_DBL  ((size_t)8388608)     // sd x L x 40        = 1,966,080
#define O_P    ((size_t)10354688)    // sd x NCH x 4096    = 3,145,728
#define O_S    ((size_t)13500416)    // 3,145,728
#define O_H    ((size_t)16646144)    // 3,145,728
#define O_YS   ((size_t)19791872)    // fb x L x 256       = 4,194,304
#define O_FT   ((size_t)23986176)    // fb x 128 x L       = 2,097,152
#define O_DP   ((size_t)26083328)    // 32,768
#define O_RT   ((size_t)26116096)    // 1,048,576
#define O_ST   ((size_t)27164672)    // 256

__device__ __forceinline__ int perm_idx(int dir, int t) {
    if (dir == 0) return t;
    if (dir == 1) return (LL - 1) - t;
    return ((t & 63) << 6) | (t >> 6);   // 64x64 transpose, self-inverse
}
__device__ __forceinline__ float softplus_fast(float x) {
    return fmaxf(x, 0.0f) + __logf(1.0f + __expf(-fabsf(x)));
}
__device__ __forceinline__ float silu_fast(float x) {
    return __fdividef(x, 1.0f + __expf(-x));
}

// ---------------------------------------------------------------------------
// K1: layernorm over channels + in_proj; write x_t[fb][l][j], z_t[fb][l][j]
// (channel-innermost so every later per-step access is coalesced)
__global__ __launch_bounds__(256) void k1_ln_inproj(
    const float* __restrict__ x1, const float* __restrict__ x2,
    const float* __restrict__ ln_g, const float* __restrict__ ln_b,
    const float* __restrict__ Win,
    float* __restrict__ x_t, float* __restrict__ z_t)
{
    __shared__ float xs[DM_ * 8];
    __shared__ float red1[64], red2[64];
    __shared__ float muS[8], rsS[8];
    int gid = blockIdx.x;
    int tile = gid & 511; int b = (gid >> 9) & 1; int f = gid >> 10;
    int l0 = tile * 8;
    int fb = f * 2 + b;
    const float* X = (f == 0 ? x1 : x2) + (size_t)b * DM_ * LL;
    int tid = threadIdx.x;
    for (int idx = tid; idx < DM_ * 8; idx += 256) {
        int c = idx >> 3, i = idx & 7;
        xs[idx] = X[(size_t)c * LL + l0 + i];
    }
    __syncthreads();
    if (tid < 64) {
        int i = tid & 7, part = tid >> 3;
        float s1 = 0.f, s2 = 0.f;
        for (int c = part * 16; c < part * 16 + 16; ++c) {
            float v = xs[c * 8 + i];
            s1 += v; s2 += v * v;
        }
        red1[tid] = s1; red2[tid] = s2;
    }
    __syncthreads();
    if (tid < 8) {
        float s1 = 0.f, s2 = 0.f;
        for (int p = 0; p < 8; ++p) { s1 += red1[p * 8 + tid]; s2 += red2[p * 8 + tid]; }
        float mu = s1 * (1.0f / 128.0f);
        float var = s2 * (1.0f / 128.0f) - mu * mu;
        muS[tid] = mu; rsS[tid] = rsqrtf(var + EPSF);
    }
    __syncthreads();
    for (int idx = tid; idx < DM_ * 8; idx += 256) {
        int c = idx >> 3, i = idx & 7;
        xs[idx] = (xs[idx] - muS[i]) * rsS[i] * ln_g[c] + ln_b[c];
    }
    __syncthreads();
    int j = tid;
    float acc0[8], acc1[8];
    #pragma unroll
    for (int i = 0; i < 8; ++i) { acc0[i] = 0.f; acc1[i] = 0.f; }
    const float* w0p = Win + (size_t)j * DM_;
    const float* w1p = Win + (size_t)(j + 256) * DM_;
    for (int c = 0; c < DM_; ++c) {
        float w0 = w0p[c], w1 = w1p[c];
        #pragma unroll
        for (int i = 0; i < 8; ++i) {
            float v = xs[c * 8 + i];
            acc0[i] += w0 * v; acc1[i] += w1 * v;
        }
    }
    float* xo = x_t + ((size_t)fb * LL + l0) * 256 + j;
    float* zo = z_t + ((size_t)fb * LL + l0) * 256 + j;
    #pragma unroll
    for (int i = 0; i < 8; ++i) { xo[i * 256] = acc0[i]; zo[i * 256] = acc1[i]; }
}

// ---------------------------------------------------------------------------
// K2: causal conv(4)+silu (rolling regs, coalesced row reads), xproj GEMM
// -> dblt[sd][t][40] (coalesced writeout via LDS)
__global__ __launch_bounds__(256) void k2_conv_xproj(
    const float* __restrict__ x_t, const float* __restrict__ conv_w,
    const float* __restrict__ conv_b, const float* __restrict__ xproj_w,
    float* __restrict__ dblt)
{
    __shared__ float xcs[DI_ * 33];
    __shared__ float dbls[RR * 33];
    int gid = blockIdx.x;
    int tile = gid & 127; int sd = gid >> 7;
    int b = sd & 1, dir = (sd >> 1) % 3, f = sd / 6;
    int fb = f * 2 + b;
    int t0 = tile * 32;
    int d = threadIdx.x;
    int dd0 = dir * DI_ + d;
    const float* xb = x_t + (size_t)fb * LL * 256 + d;
    float w0 = conv_w[dd0 * 4 + 0], w1 = conv_w[dd0 * 4 + 1];
    float w2 = conv_w[dd0 * 4 + 2], w3 = conv_w[dd0 * 4 + 3];
    float cb = conv_b[dd0];
    float r0 = (t0 >= 3) ? xb[(size_t)perm_idx(dir, t0 - 3) * 256] : 0.f;
    float r1 = (t0 >= 2) ? xb[(size_t)perm_idx(dir, t0 - 2) * 256] : 0.f;
    float r2 = (t0 >= 1) ? xb[(size_t)perm_idx(dir, t0 - 1) * 256] : 0.f;
    for (int tt = 0; tt < 32; ++tt) {
        float r3 = xb[(size_t)perm_idx(dir, t0 + tt) * 256];
        float v = cb + w0 * r0 + w1 * r1 + w2 * r2 + w3 * r3;
        xcs[d * 33 + tt] = silu_fast(v);
        r0 = r1; r1 = r2; r2 = r3;
    }
    __syncthreads();
    const float* xpw = xproj_w + (size_t)dir * RR * DI_;
    #pragma unroll
    for (int k = 0; k < 5; ++k) {
        int idx = threadIdx.x + k * 256;
        int r = idx >> 5, tt = idx & 31;
        const float* wr = xpw + (size_t)r * DI_;
        float acc = 0.f;
        for (int dd = 0; dd < DI_; ++dd) acc += xcs[dd * 33 + tt] * wr[dd];
        dbls[r * 33 + tt] = acc;
    }
    __syncthreads();
    float* dro = dblt + ((size_t)sd * LL + t0) * RR;
    for (int i = threadIdx.x; i < 32 * RR; i += 256) {
        int tt = i / RR, r = i - tt * RR;
        dro[i] = dbls[r * 33 + tt];
    }
}

// ---------------------------------------------------------------------------
// K3: scan pass 1 — thread owns (d, all 16 states). Per chunk: P[n]=prod a,
// S[n]=local state from h0=0. conv+dt recomputed in-pass (cheap, saves 100MB).
__global__ __launch_bounds__(256) void k3_pass1(
    const float* __restrict__ x_t, const float* __restrict__ dblt,
    const float* __restrict__ conv_w, const float* __restrict__ conv_b,
    const float* __restrict__ dtw, const float* __restrict__ dtbp,
    const float* __restrict__ A_log,
    float* __restrict__ Pb, float* __restrict__ Sb)
{
    __shared__ float dbs[CHL * RR];   // 2560 floats
    int bid = blockIdx.x;
    int chunk = bid & (NCH - 1); int sd = bid >> 6;
    int b = sd & 1, dir = (sd >> 1) % 3, f = sd / 6;
    int fb = f * 2 + b;
    int d = threadIdx.x;
    int t0 = chunk * CHL;
    const float* dsrc = dblt + ((size_t)sd * LL + t0) * RR;
    for (int i = d; i < CHL * RR; i += 256) dbs[i] = dsrc[i];
    int dd0 = dir * DI_ + d;
    float w0 = conv_w[dd0 * 4 + 0], w1 = conv_w[dd0 * 4 + 1];
    float w2 = conv_w[dd0 * 4 + 2], w3 = conv_w[dd0 * 4 + 3];
    float cb = conv_b[dd0];
    float pw[DTRN];
    #pragma unroll
    for (int r = 0; r < DTRN; ++r) pw[r] = dtw[dd0 * DTRN + r];
    float dtb = dtbp[dd0];
    float An[16];
    #pragma unroll
    for (int n = 0; n < 16; ++n) An[n] = -__expf(A_log[dd0 * 16 + n]);
    const float* xb = x_t + (size_t)fb * LL * 256 + d;
    float r0 = (t0 >= 3) ? xb[(size_t)perm_idx(dir, t0 - 3) * 256] : 0.f;
    float r1 = (t0 >= 2) ? xb[(size_t)perm_idx(dir, t0 - 2) * 256] : 0.f;
    float r2 = (t0 >= 1) ? xb[(size_t)perm_idx(dir, t0 - 1) * 256] : 0.f;
    float P[16], S[16];
    #pragma unroll
    for (int n = 0; n < 16; ++n) { P[n] = 1.0f; S[n] = 0.0f; }
    __syncthreads();
    for (int s = 0; s < CHL; ++s) {
        int t = t0 + s;
        float r3 = xb[(size_t)perm_idx(dir, t) * 256];
        float xc = cb + w0 * r0 + w1 * r1 + w2 * r2 + w3 * r3;
        r0 = r1; r1 = r2; r2 = r3;
        float xv = silu_fast(xc);
        const float* dr = dbs + s * RR;
        float da = dtb;
        #pragma unroll
        for (int r = 0; r < DTRN; ++r) da += pw[r] * dr[r];
        float dtv = softplus_fast(da);
        float u = dtv * xv;
        const float4* dq = (const float4*)(dr + DTRN);
        float4 B0 = dq[0], B1 = dq[1], B2 = dq[2], B3 = dq[3];
        #define PS_STEP(i, bv) { float a = __expf(dtv * An[i]); P[i] *= a; S[i] = fmaf(S[i], a, u * (bv)); }
        PS_STEP(0, B0.x) PS_STEP(1, B0.y) PS_STEP(2, B0.z) PS_STEP(3, B0.w)
        PS_STEP(4, B1.x) PS_STEP(5, B1.y) PS_STEP(6, B1.z) PS_STEP(7, B1.w)
        PS_STEP(8, B2.x) PS_STEP(9, B2.y) PS_STEP(10, B2.z) PS_STEP(11, B2.w)
        PS_STEP(12, B3.x) PS_STEP(13, B3.y) PS_STEP(14, B3.z) PS_STEP(15, B3.w)
        #undef PS_STEP
    }
    size_t off = ((size_t)sd * NCH + chunk) * 4096 + d * 16;
    float4* pp = (float4*)(Pb + off);
    float4* ss = (float4*)(Sb + off);
    pp[0] = make_float4(P[0], P[1], P[2], P[3]);
    pp[1] = make_float4(P[4], P[5], P[6], P[7]);
    pp[2] = make_float4(P[8], P[9], P[10], P[11]);
    pp[3] = make_float4(P[12], P[13], P[14], P[15]);
    ss[0] = make_float4(S[0], S[1], S[2], S[3]);
    ss[1] = make_float4(S[4], S[5], S[6], S[7]);
    ss[2] = make_float4(S[8], S[9], S[10], S[11]);
    ss[3] = make_float4(S[12], S[13], S[14], S[15]);
}

// ---------------------------------------------------------------------------
// K4: propagate chunk-boundary states sequentially across NCH chunks
__global__ __launch_bounds__(256) void k4_combine(
    const float* __restrict__ Pb, const float* __restrict__ Sb,
    float* __restrict__ Hb)
{
    int id = blockIdx.x * 256 + threadIdx.x;   // 49152 = 12 sd * 4096 dn
    int sd = id >> 12; int dn = id & 4095;
    size_t base = (size_t)sd * NCH * 4096 + dn;
    float h = 0.f;
    for (int c = 0; c < NCH; ++c) {
        size_t idx = base + (size_t)c * 4096;
        Hb[idx] = h;
        h = Pb[idx] * h + Sb[idx];
    }
}

// ---------------------------------------------------------------------------
// K5: scan pass 3 — rerun chunks with h0; y = sum_n h*C + D*xv;
// one coalesced atomicAdd per (t,d) into ysum[fb][lp][d]. silu(z) deferred to K6.
__global__ __launch_bounds__(256) void k5_pass3(
    const float* __restrict__ x_t, const float* __restrict__ dblt,
    const float* __restrict__ conv_w, const float* __restrict__ conv_b,
    const float* __restrict__ dtw, const float* __restrict__ dtbp,
    const float* __restrict__ A_log, const float* __restrict__ Dv,
    const float* __restrict__ Hb, float* __restrict__ ysum)
{
    __shared__ float dbs[CHL * RR];
    int bid = blockIdx.x;
    int chunk = bid & (NCH - 1); int sd = bid >> 6;
    int b = sd & 1, dir = (sd >> 1) % 3, f = sd / 6;
    int fb = f * 2 + b;
    int d = threadIdx.x;
    int t0 = chunk * CHL;
    const float* dsrc = dblt + ((size_t)sd * LL + t0) * RR;
    for (int i = d; i < CHL * RR; i += 256) dbs[i] = dsrc[i];
    int dd0 = dir * DI_ + d;
    float w0 = conv_w[dd0 * 4 + 0], w1 = conv_w[dd0 * 4 + 1];
    float w2 = conv_w[dd0 * 4 + 2], w3 = conv_w[dd0 * 4 + 3];
    float cb = conv_b[dd0];
    float pw[DTRN];
    #pragma unroll
    for (int r = 0; r < DTRN; ++r) pw[r] = dtw[dd0 * DTRN + r];
    float dtb = dtbp[dd0];
    float Dd = Dv[dd0];
    float An[16];
    #pragma unroll
    for (int n = 0; n < 16; ++n) An[n] = -__expf(A_log[dd0 * 16 + n]);
    size_t hoff = ((size_t)sd * NCH + chunk) * 4096 + d * 16;
    const float4* hq = (const float4*)(Hb + hoff);
    float4 h0q = hq[0], h1q = hq[1], h2q = hq[2], h3q = hq[3];
    float h[16] = { h0q.x, h0q.y, h0q.z, h0q.w, h1q.x, h1q.y, h1q.z, h1q.w,
                    h2q.x, h2q.y, h2q.z, h2q.w, h3q.x, h3q.y, h3q.z, h3q.w };
    const float* xb = x_t + (size_t)fb * LL * 256 + d;
    float* yb = ysum + (size_t)fb * LL * 256 + d;
    float r0 = (t0 >= 3) ? xb[(size_t)perm_idx(dir, t0 - 3) * 256] : 0.f;
    float r1 = (t0 >= 2) ? xb[(size_t)perm_idx(dir, t0 - 2) * 256] : 0.f;
    float r2 = (t0 >= 1) ? xb[(size_t)perm_idx(dir, t0 - 1) * 256] : 0.f;
    __syncthreads();
    for (int s = 0; s < CHL; ++s) {
        int t = t0 + s;
        float r3 = xb[(size_t)perm_idx(dir, t) * 256];
        float xc = cb + w0 * r0 + w1 * r1 + w2 * r2 + w3 * r3;
        r0 = r1; r1 = r2; r2 = r3;
        float xv = silu_fast(xc);
        const float* dr = dbs + s * RR;
        float da = dtb;
        #pragma unroll
        for (int r = 0; r < DTRN; ++r) da += pw[r] * dr[r];
        float dtv = softplus_fast(da);
        float u = dtv * xv;
        const float4* dq = (const float4*)(dr + DTRN);
        float4 B0 = dq[0], B1 = dq[1], B2 = dq[2], B3 = dq[3];
        float4 C0 = dq[4], C1 = dq[5], C2 = dq[6], C3 = dq[7];
        float y = 0.f;
        #define H_STEP(i, bv, cv) { float a = __expf(dtv * An[i]); h[i] = fmaf(h[i], a, u * (bv)); y = fmaf(h[i], (cv), y); }
        H_STEP(0, B0.x, C0.x) H_STEP(1, B0.y, C0.y) H_STEP(2, B0.z, C0.z) H_STEP(3, B0.w, C0.w)
        H_STEP(4, B1.x, C1.x) H_STEP(5, B1.y, C1.y) H_STEP(6, B1.z, C1.z) H_STEP(7, B1.w, C1.w)
        H_STEP(8, B2.x, C2.x) H_STEP(9, B2.y, C2.y) H_STEP(10, B2.z, C2.z) H_STEP(11, B2.w, C2.w)
        H_STEP(12, B3.x, C3.x) H_STEP(13, B3.y, C3.y) H_STEP(14, B3.z, C3.z) H_STEP(15, B3.w, C3.w)
        #undef H_STEP
        int lp = perm_idx(dir, t);
        atomicAdd(yb + (size_t)lp * 256, fmaf(Dd, xv, y));
    }
}

// ---------------------------------------------------------------------------
// K6: u[l][d] = ysum[l][d]*silu(z[l][d]); feat[fb][c][l] = sum_d Wout[c][d]*u
__global__ __launch_bounds__(256) void k6_outproj(
    const float* __restrict__ ysum, const float* __restrict__ z_t,
    const float* __restrict__ Wout, float* __restrict__ feat)
{
    __shared__ float us[32 * 257];
    int gid = blockIdx.x;
    int ltile = gid & 127; int fb = gid >> 7;
    int l0 = ltile * 32;
    int tid = threadIdx.x;
    for (int i = tid; i < 32 * 256; i += 256) {
        int tt = i >> 8, dd = i & 255;
        size_t gi = ((size_t)fb * LL + l0 + tt) * 256 + dd;
        us[tt * 257 + dd] = ysum[gi] * silu_fast(z_t[gi]);
    }
    __syncthreads();
    int tt = tid & 31, cg = tid >> 5;
    int c0 = cg * 16;
    float acc[16];
    #pragma unroll
    for (int k = 0; k < 16; ++k) acc[k] = 0.f;
    for (int dd = 0; dd < DI_; ++dd) {
        float v = us[tt * 257 + dd];
        #pragma unroll
        for (int k = 0; k < 16; ++k) acc[k] += Wout[(size_t)(c0 + k) * DI_ + dd] * v;
    }
    #pragma unroll
    for (int k = 0; k < 16; ++k)
        feat[((size_t)fb * DM_ + c0 + k) * LL + l0 + tt] = acc[k];
}

// ---------------------------------------------------------------------------
// K7a: dp[b][c][d] = sum_l featA[b][c][l]*featB[b][d][l]
__global__ __launch_bounds__(256) void k7a_dp(
    const float* __restrict__ feat, float* __restrict__ dp)
{
    __shared__ float As[16 * 132];
    __shared__ float Bs[16 * 132];
    int gid = blockIdx.x;
    int lc = gid & 7; int dg = (gid >> 3) & 7; int cg = (gid >> 6) & 7; int b = (gid >> 9) & 1;
    int tid = threadIdx.x;
    int cc = tid & 15, dd = tid >> 4;
    int c0 = cg * 16, d0 = dg * 16, l0 = lc * 512;
    const float* fa = feat + ((size_t)(0 * 2 + b) * DM_) * LL;
    const float* fb = feat + ((size_t)(1 * 2 + b) * DM_) * LL;
    float acc = 0.f;
    for (int st = 0; st < 4; ++st) {
        __syncthreads();
        #pragma unroll
        for (int k = 0; k < 8; ++k) {
            int idx = tid + k * 256;
            int c = idx >> 7, ll = idx & 127;
            As[c * 132 + ll] = fa[(size_t)(c0 + c) * LL + l0 + st * 128 + ll];
            Bs[c * 132 + ll] = fb[(size_t)(d0 + c) * LL + l0 + st * 128 + ll];
        }
        __syncthreads();
        for (int ll = 0; ll < 128; ++ll)
            acc += As[cc * 132 + ll] * Bs[dd * 132 + ll];
    }
    atomicAdd(&dp[((size_t)b * DM_ + c0 + cc) * DM_ + d0 + dd], acc);
}

// ---------------------------------------------------------------------------
// K7b: res_t[b][l][c] = sum_d dp[b][c][d]*featB[b][d][l]; + BN channel stats
__global__ __launch_bounds__(256) void k7b_res(
    const float* __restrict__ feat, const float* __restrict__ dp,
    float* __restrict__ res_t, float* __restrict__ stats)
{
    __shared__ float fBs[DM_ * 33];
    __shared__ float red[256];
    int gid = blockIdx.x;
    int ltile = gid & 127; int b = gid >> 7;
    int l0 = ltile * 32;
    int tid = threadIdx.x;
    const float* fb = feat + ((size_t)(2 + b) * DM_) * LL;
    for (int idx = tid; idx < DM_ * 32; idx += 256) {
        int d = idx >> 5, ll = idx & 31;
        fBs[d * 33 + ll] = fb[(size_t)d * LL + l0 + ll];
    }
    __syncthreads();
    int ll = tid & 31, cg = tid >> 5;
    const float* dpb = dp + (size_t)b * DM_ * DM_;
    float acc[16];
    #pragma unroll
    for (int k = 0; k < 16; ++k) acc[k] = 0.f;
    for (int d = 0; d < DM_; ++d) {
        float v = fBs[d * 33 + ll];
        #pragma unroll
        for (int k = 0; k < 16; ++k)
            acc[k] += dpb[(size_t)(cg * 16 + k) * DM_ + d] * v;
    }
    float s1 = 0.f, s2 = 0.f;
    float* out = res_t + ((size_t)b * LL + l0 + ll) * DM_ + cg * 16;
    #pragma unroll
    for (int k = 0; k < 16; ++k) {
        out[k] = acc[k];
        s1 += acc[k]; s2 += acc[k] * acc[k];
    }
    red[tid] = s1; __syncthreads();
    for (int s = 128; s > 0; s >>= 1) { if (tid < s) red[tid] += red[tid + s]; __syncthreads(); }
    if (tid == 0) atomicAdd(&stats[ltile], red[0]);
    __syncthreads();
    red[tid] = s2; __syncthreads();
    for (int s = 128; s > 0; s >>= 1) { if (tid < s) red[tid] += red[tid + s]; __syncthreads(); }
    if (tid == 0) atomicAdd(&stats[DM_ + ltile], red[0]);
}

// ---------------------------------------------------------------------------
// K7d: batchnorm finalize; res_t flat index == output flat index
__global__ __launch_bounds__(256) void k7d_bn(
    const float* __restrict__ res_t, const float* __restrict__ stats,
    const float* __restrict__ bn_g, const float* __restrict__ bn_b,
    float* __restrict__ outp)
{
    int i = blockIdx.x * 256 + threadIdx.x;   // 1048576 total
    int m = i & (524288 - 1);
    int cp = m >> 12;
    float mu = stats[cp] * (1.0f / 8192.0f);
    float var = stats[DM_ + cp] * (1.0f / 8192.0f) - mu * mu;
    float v = res_t[i];
    outp[i] = (v - mu) * rsqrtf(var + EPSF) * bn_g[cp] + bn_b[cp];
}

// ---------------------------------------------------------------------------
extern "C" void kernel_launch(void* const* d_in, const int* in_sizes, int n_in,
                              void* d_out, int out_size, void* d_ws, size_t ws_size,
                              hipStream_t stream)
{
    (void)in_sizes; (void)n_in; (void)out_size; (void)ws_size;
    const float* x1   = (const float*)d_in[0];
    const float* x2   = (const float*)d_in[1];
    const float* ln_g = (const float*)d_in[2];
    const float* ln_b = (const float*)d_in[3];
    const float* Win  = (const float*)d_in[4];
    const float* cw   = (const float*)d_in[5];
    const float* cb   = (const float*)d_in[6];
    const float* xpw  = (const float*)d_in[7];
    const float* dpw  = (const float*)d_in[8];
    const float* dpb  = (const float*)d_in[9];
    const float* Alog = (const float*)d_in[10];
    const float* Dv   = (const float*)d_in[11];
    const float* Wout = (const float*)d_in[12];
    const float* bn_g = (const float*)d_in[13];
    const float* bn_b = (const float*)d_in[14];
    float* outp = (float*)d_out;
    float* ws = (float*)d_ws;

    float* x_t  = ws + O_XT;
    float* z_t  = ws + O_ZT;
    float* dblt = ws + O_DBL;
    float* Pb   = ws + O_P;
    float* Sb   = ws + O_S;
    float* Hb   = ws + O_H;
    float* ysum = ws + O_YS;
    float* feat = ws + O_FT;
    float* dpB  = ws + O_DP;
    float* rest = ws + O_RT;
    float* stat = ws + O_ST;

    hipMemsetAsync(ysum, 0, (size_t)4194304 * 4, stream);
    hipMemsetAsync(dpB, 0, (size_t)32768 * 4, stream);
    hipMemsetAsync(stat, 0, (size_t)256 * 4, stream);

    k1_ln_inproj<<<2048, 256, 0, stream>>>(x1, x2, ln_g, ln_b, Win, x_t, z_t);
    k2_conv_xproj<<<1536, 256, 0, stream>>>(x_t, cw, cb, xpw, dblt);
    k3_pass1<<<768, 256, 0, stream>>>(x_t, dblt, cw, cb, dpw, dpb, Alog, Pb, Sb);
    k4_combine<<<192, 256, 0, stream>>>(Pb, Sb, Hb);
    k5_pass3<<<768, 256, 0, stream>>>(x_t, dblt, cw, cb, dpw, dpb, Alog, Dv, Hb, ysum);
    k6_outproj<<<512, 256, 0, stream>>>(ysum, z_t, Wout, feat);
    k7a_dp<<<1024, 256, 0, stream>>>(feat, dpB);
    k7b_res<<<256, 256, 0, stream>>>(feat, dpB, rest, stat);
    k7d_bn<<<4096, 256, 0, stream>>>(rest, stat, bn_g, bn_b, outp);
}

// Round 3
// 432.853 us; speedup vs baseline: 2.7512x; 1.4415x over previous
//
#include <hip/hip_runtime.h>
#include <math.h>

// Problem constants
#define DM_ 128       // model dim
#define LL 4096       // sequence length (64*64)
#define DI_ 256       // inner dim
#define DTRN 8        // dt rank
#define DSN 16        // state dim
#define RR 40         // DTR + 2*DS
#define NCH 64        // scan chunks
#define CHL 64        // chunk length
#define EPSF 1e-5f

// workspace layout (float offsets), total ~30.3M floats = 121 MB
#define O_XT   ((size_t)0)           // fb x L x 256       = 4,194,304
#define O_ZT   ((size_t)4194304)     // fb x L x 256       = 4,194,304
#define O_XN   ((size_t)8388608)     // fb x L x 128       = 2,097,152
#define O_DBL  ((size_t)10485760)    // sd x L x 40        = 1,966,080
#define O_P    ((size_t)12451840)    // sd x NCH x 4096    = 3,145,728
#define O_S    ((size_t)15597568)    // 3,145,728
#define O_H    ((size_t)18743296)    // 3,145,728
#define O_YS   ((size_t)21889024)    // fb x L x 256       = 4,194,304
#define O_FT   ((size_t)26083328)    // fb x 128 x L       = 2,097,152
#define O_DP   ((size_t)28180480)    // 32,768
#define O_RT   ((size_t)28213248)    // 1,048,576
#define O_ST   ((size_t)29261824)    // 256
#define O_PART ((size_t)29262080)    // 32 x 32768         = 1,048,576

__device__ __forceinline__ int perm_idx(int dir, int t) {
    if (dir == 0) return t;
    if (dir == 1) return (LL - 1) - t;
    return ((t & 63) << 6) | (t >> 6);   // 64x64 transpose, self-inverse
}
__device__ __forceinline__ float softplus_fast(float x) {
    return fmaxf(x, 0.0f) + __logf(1.0f + __expf(-fabsf(x)));
}
__device__ __forceinline__ float silu_fast(float x) {
    return __fdividef(x, 1.0f + __expf(-x));
}

// ---------------------------------------------------------------------------
// K0: layernorm over channels -> xn[fb][l][128] (c-innermost)
__global__ __launch_bounds__(256) void k0_ln(
    const float* __restrict__ x1, const float* __restrict__ x2,
    const float* __restrict__ ln_g, const float* __restrict__ ln_b,
    float* __restrict__ xn)
{
    __shared__ float xs[128 * 65];
    __shared__ float red1[256], red2[256];
    __shared__ float muS[64], rsS[64];
    int bid = blockIdx.x;
    int lt = bid & 63; int fb = bid >> 6;
    int f = fb >> 1, b = fb & 1;
    int l0 = lt * 64; int tid = threadIdx.x;
    const float* X = (f == 0 ? x1 : x2) + (size_t)b * DM_ * LL;
    for (int idx = tid; idx < 128 * 64; idx += 256) {
        int c = idx >> 6, l = idx & 63;
        xs[c * 65 + l] = X[(size_t)c * LL + l0 + l];
    }
    __syncthreads();
    {
        int l = tid & 63, part = tid >> 6;
        float s1 = 0.f, s2 = 0.f;
        for (int c = part * 32; c < part * 32 + 32; ++c) {
            float v = xs[c * 65 + l]; s1 += v; s2 += v * v;
        }
        red1[tid] = s1; red2[tid] = s2;
    }
    __syncthreads();
    if (tid < 64) {
        float a1 = red1[tid] + red1[64 + tid] + red1[128 + tid] + red1[192 + tid];
        float a2 = red2[tid] + red2[64 + tid] + red2[128 + tid] + red2[192 + tid];
        float mu = a1 * (1.0f / 128.0f);
        float var = a2 * (1.0f / 128.0f) - mu * mu;
        muS[tid] = mu; rsS[tid] = rsqrtf(var + EPSF);
    }
    __syncthreads();
    for (int idx = tid; idx < 8192; idx += 256) {
        int c = idx & 127, l = idx >> 7;
        float v = (xs[c * 65 + l] - muS[l]) * rsS[l] * ln_g[c] + ln_b[c];
        xn[((size_t)fb * LL + l0 + l) * 128 + c] = v;
    }
}

// ---------------------------------------------------------------------------
// K1: in_proj GEMM: out[m][j] = sum_c xn[m][c]*Win[j][c]; M=16384,N=512,K=128
// 64x64 tiles, 4x4 microtile, k-major LDS.
__global__ __launch_bounds__(256) void k1_gemm(
    const float* __restrict__ xn, const float* __restrict__ Win,
    float* __restrict__ x_t, float* __restrict__ z_t)
{
    __shared__ float As[64 * 68];
    __shared__ float Ws[64 * 68];
    int bid = blockIdx.x;
    int jt = bid & 7; int mt = bid >> 3;
    int m0 = mt * 64, j0 = jt * 64;
    int tid = threadIdx.x;
    int tx = tid & 15, ty = tid >> 4;
    float acc[4][4];
    #pragma unroll
    for (int i = 0; i < 4; ++i)
        #pragma unroll
        for (int j = 0; j < 4; ++j) acc[i][j] = 0.f;
    for (int kt = 0; kt < 2; ++kt) {
        int c0 = kt * 64;
        __syncthreads();
        for (int idx = tid; idx < 4096; idx += 256) {
            int r = idx >> 6, cc = idx & 63;
            As[cc * 68 + r] = xn[(size_t)(m0 + r) * 128 + c0 + cc];
            Ws[cc * 68 + r] = Win[(size_t)(j0 + r) * 128 + c0 + cc];
        }
        __syncthreads();
        for (int k = 0; k < 64; ++k) {
            float4 av = *(const float4*)&As[k * 68 + ty * 4];
            float4 wv = *(const float4*)&Ws[k * 68 + tx * 4];
            acc[0][0] = fmaf(av.x, wv.x, acc[0][0]); acc[0][1] = fmaf(av.x, wv.y, acc[0][1]);
            acc[0][2] = fmaf(av.x, wv.z, acc[0][2]); acc[0][3] = fmaf(av.x, wv.w, acc[0][3]);
            acc[1][0] = fmaf(av.y, wv.x, acc[1][0]); acc[1][1] = fmaf(av.y, wv.y, acc[1][1]);
            acc[1][2] = fmaf(av.y, wv.z, acc[1][2]); acc[1][3] = fmaf(av.y, wv.w, acc[1][3]);
            acc[2][0] = fmaf(av.z, wv.x, acc[2][0]); acc[2][1] = fmaf(av.z, wv.y, acc[2][1]);
            acc[2][2] = fmaf(av.z, wv.z, acc[2][2]); acc[2][3] = fmaf(av.z, wv.w, acc[2][3]);
            acc[3][0] = fmaf(av.w, wv.x, acc[3][0]); acc[3][1] = fmaf(av.w, wv.y, acc[3][1]);
            acc[3][2] = fmaf(av.w, wv.z, acc[3][2]); acc[3][3] = fmaf(av.w, wv.w, acc[3][3]);
        }
    }
    float* dst = (j0 < 256) ? (x_t + j0) : (z_t + j0 - 256);
    #pragma unroll
    for (int i = 0; i < 4; ++i) {
        size_t m = (size_t)(m0 + ty * 4 + i);
        float4 v = make_float4(acc[i][0], acc[i][1], acc[i][2], acc[i][3]);
        *(float4*)&dst[m * 256 + tx * 4] = v;
    }
}

// ---------------------------------------------------------------------------
// K2: causal conv(4)+silu (rolling regs, coalesced row reads), xproj GEMM
// -> dblt[sd][t][40]
__global__ __launch_bounds__(256) void k2_conv_xproj(
    const float* __restrict__ x_t, const float* __restrict__ conv_w,
    const float* __restrict__ conv_b, const float* __restrict__ xproj_w,
    float* __restrict__ dblt)
{
    __shared__ float xcs[DI_ * 33];
    __shared__ float dbls[RR * 33];
    int gid = blockIdx.x;
    int tile = gid & 127; int sd = gid >> 7;
    int b = sd & 1, dir = (sd >> 1) % 3, f = sd / 6;
    int fb = f * 2 + b;
    int t0 = tile * 32;
    int d = threadIdx.x;
    int dd0 = dir * DI_ + d;
    const float* xb = x_t + (size_t)fb * LL * 256 + d;
    float w0 = conv_w[dd0 * 4 + 0], w1 = conv_w[dd0 * 4 + 1];
    float w2 = conv_w[dd0 * 4 + 2], w3 = conv_w[dd0 * 4 + 3];
    float cb = conv_b[dd0];
    float r0 = (t0 >= 3) ? xb[(size_t)perm_idx(dir, t0 - 3) * 256] : 0.f;
    float r1 = (t0 >= 2) ? xb[(size_t)perm_idx(dir, t0 - 2) * 256] : 0.f;
    float r2 = (t0 >= 1) ? xb[(size_t)perm_idx(dir, t0 - 1) * 256] : 0.f;
    for (int tt = 0; tt < 32; ++tt) {
        float r3 = xb[(size_t)perm_idx(dir, t0 + tt) * 256];
        float v = cb + w0 * r0 + w1 * r1 + w2 * r2 + w3 * r3;
        xcs[d * 33 + tt] = silu_fast(v);
        r0 = r1; r1 = r2; r2 = r3;
    }
    __syncthreads();
    const float* xpw = xproj_w + (size_t)dir * RR * DI_;
    #pragma unroll
    for (int k = 0; k < 5; ++k) {
        int idx = threadIdx.x + k * 256;
        int r = idx >> 5, tt = idx & 31;
        const float* wr = xpw + (size_t)r * DI_;
        float acc = 0.f;
        for (int dd = 0; dd < DI_; ++dd) acc += xcs[dd * 33 + tt] * wr[dd];
        dbls[r * 33 + tt] = acc;
    }
    __syncthreads();
    float* dro = dblt + ((size_t)sd * LL + t0) * RR;
    for (int i = threadIdx.x; i < 32 * RR; i += 256) {
        int tt = i / RR, r = i - tt * RR;
        dro[i] = dbls[r * 33 + tt];
    }
}

// ---------------------------------------------------------------------------
// K3: scan pass 1 — thread owns (d, all 16 states). Per chunk: P[n]=prod a,
// S[n]=local state from h0=0.
__global__ __launch_bounds__(256) void k3_pass1(
    const float* __restrict__ x_t, const float* __restrict__ dblt,
    const float* __restrict__ conv_w, const float* __restrict__ conv_b,
    const float* __restrict__ dtw, const float* __restrict__ dtbp,
    const float* __restrict__ A_log,
    float* __restrict__ Pb, float* __restrict__ Sb)
{
    __shared__ float dbs[CHL * RR];   // 2560 floats
    int bid = blockIdx.x;
    int chunk = bid & (NCH - 1); int sd = bid >> 6;
    int b = sd & 1, dir = (sd >> 1) % 3, f = sd / 6;
    int fb = f * 2 + b;
    int d = threadIdx.x;
    int t0 = chunk * CHL;
    const float* dsrc = dblt + ((size_t)sd * LL + t0) * RR;
    for (int i = d; i < CHL * RR; i += 256) dbs[i] = dsrc[i];
    int dd0 = dir * DI_ + d;
    float w0 = conv_w[dd0 * 4 + 0], w1 = conv_w[dd0 * 4 + 1];
    float w2 = conv_w[dd0 * 4 + 2], w3 = conv_w[dd0 * 4 + 3];
    float cb = conv_b[dd0];
    float pw[DTRN];
    #pragma unroll
    for (int r = 0; r < DTRN; ++r) pw[r] = dtw[dd0 * DTRN + r];
    float dtb = dtbp[dd0];
    float An[16];
    #pragma unroll
    for (int n = 0; n < 16; ++n) An[n] = -__expf(A_log[dd0 * 16 + n]);
    const float* xb = x_t + (size_t)fb * LL * 256 + d;
    float r0 = (t0 >= 3) ? xb[(size_t)perm_idx(dir, t0 - 3) * 256] : 0.f;
    float r1 = (t0 >= 2) ? xb[(size_t)perm_idx(dir, t0 - 2) * 256] : 0.f;
    float r2 = (t0 >= 1) ? xb[(size_t)perm_idx(dir, t0 - 1) * 256] : 0.f;
    float P[16], S[16];
    #pragma unroll
    for (int n = 0; n < 16; ++n) { P[n] = 1.0f; S[n] = 0.0f; }
    __syncthreads();
    for (int s = 0; s < CHL; ++s) {
        int t = t0 + s;
        float r3 = xb[(size_t)perm_idx(dir, t) * 256];
        float xc = cb + w0 * r0 + w1 * r1 + w2 * r2 + w3 * r3;
        r0 = r1; r1 = r2; r2 = r3;
        float xv = silu_fast(xc);
        const float* dr = dbs + s * RR;
        float da = dtb;
        #pragma unroll
        for (int r = 0; r < DTRN; ++r) da += pw[r] * dr[r];
        float dtv = softplus_fast(da);
        float u = dtv * xv;
        const float4* dq = (const float4*)(dr + DTRN);
        float4 B0 = dq[0], B1 = dq[1], B2 = dq[2], B3 = dq[3];
        #define PS_STEP(i, bv) { float a = __expf(dtv * An[i]); P[i] *= a; S[i] = fmaf(S[i], a, u * (bv)); }
        PS_STEP(0, B0.x) PS_STEP(1, B0.y) PS_STEP(2, B0.z) PS_STEP(3, B0.w)
        PS_STEP(4, B1.x) PS_STEP(5, B1.y) PS_STEP(6, B1.z) PS_STEP(7, B1.w)
        PS_STEP(8, B2.x) PS_STEP(9, B2.y) PS_STEP(10, B2.z) PS_STEP(11, B2.w)
        PS_STEP(12, B3.x) PS_STEP(13, B3.y) PS_STEP(14, B3.z) PS_STEP(15, B3.w)
        #undef PS_STEP
    }
    size_t off = ((size_t)sd * NCH + chunk) * 4096 + d * 16;
    float4* pp = (float4*)(Pb + off);
    float4* ss = (float4*)(Sb + off);
    pp[0] = make_float4(P[0], P[1], P[2], P[3]);
    pp[1] = make_float4(P[4], P[5], P[6], P[7]);
    pp[2] = make_float4(P[8], P[9], P[10], P[11]);
    pp[3] = make_float4(P[12], P[13], P[14], P[15]);
    ss[0] = make_float4(S[0], S[1], S[2], S[3]);
    ss[1] = make_float4(S[4], S[5], S[6], S[7]);
    ss[2] = make_float4(S[8], S[9], S[10], S[11]);
    ss[3] = make_float4(S[12], S[13], S[14], S[15]);
}

// ---------------------------------------------------------------------------
// K4: propagate chunk-boundary states sequentially across NCH chunks
__global__ __launch_bounds__(256) void k4_combine(
    const float* __restrict__ Pb, const float* __restrict__ Sb,
    float* __restrict__ Hb)
{
    int id = blockIdx.x * 256 + threadIdx.x;   // 49152 = 12 sd * 4096 dn
    int sd = id >> 12; int dn = id & 4095;
    size_t base = (size_t)sd * NCH * 4096 + dn;
    float h = 0.f;
    for (int c = 0; c < NCH; ++c) {
        size_t idx = base + (size_t)c * 4096;
        Hb[idx] = h;
        h = Pb[idx] * h + Sb[idx];
    }
}

// ---------------------------------------------------------------------------
// K5: scan pass 3 — rerun chunks with h0; y = sum_n h*C + D*xv;
// one coalesced atomicAdd per (t,d) into ysum[fb][lp][d].
__global__ __launch_bounds__(256) void k5_pass3(
    const float* __restrict__ x_t, const float* __restrict__ dblt,
    const float* __restrict__ conv_w, const float* __restrict__ conv_b,
    const float* __restrict__ dtw, const float* __restrict__ dtbp,
    const float* __restrict__ A_log, const float* __restrict__ Dv,
    const float* __restrict__ Hb, float* __restrict__ ysum)
{
    __shared__ float dbs[CHL * RR];
    int bid = blockIdx.x;
    int chunk = bid & (NCH - 1); int sd = bid >> 6;
    int b = sd & 1, dir = (sd >> 1) % 3, f = sd / 6;
    int fb = f * 2 + b;
    int d = threadIdx.x;
    int t0 = chunk * CHL;
    const float* dsrc = dblt + ((size_t)sd * LL + t0) * RR;
    for (int i = d; i < CHL * RR; i += 256) dbs[i] = dsrc[i];
    int dd0 = dir * DI_ + d;
    float w0 = conv_w[dd0 * 4 + 0], w1 = conv_w[dd0 * 4 + 1];
    float w2 = conv_w[dd0 * 4 + 2], w3 = conv_w[dd0 * 4 + 3];
    float cb = conv_b[dd0];
    float pw[DTRN];
    #pragma unroll
    for (int r = 0; r < DTRN; ++r) pw[r] = dtw[dd0 * DTRN + r];
    float dtb = dtbp[dd0];
    float Dd = Dv[dd0];
    float An[16];
    #pragma unroll
    for (int n = 0; n < 16; ++n) An[n] = -__expf(A_log[dd0 * 16 + n]);
    size_t hoff = ((size_t)sd * NCH + chunk) * 4096 + d * 16;
    const float4* hq = (const float4*)(Hb + hoff);
    float4 h0q = hq[0], h1q = hq[1], h2q = hq[2], h3q = hq[3];
    float h[16] = { h0q.x, h0q.y, h0q.z, h0q.w, h1q.x, h1q.y, h1q.z, h1q.w,
                    h2q.x, h2q.y, h2q.z, h2q.w, h3q.x, h3q.y, h3q.z, h3q.w };
    const float* xb = x_t + (size_t)fb * LL * 256 + d;
    float* yb = ysum + (size_t)fb * LL * 256 + d;
    float r0 = (t0 >= 3) ? xb[(size_t)perm_idx(dir, t0 - 3) * 256] : 0.f;
    float r1 = (t0 >= 2) ? xb[(size_t)perm_idx(dir, t0 - 2) * 256] : 0.f;
    float r2 = (t0 >= 1) ? xb[(size_t)perm_idx(dir, t0 - 1) * 256] : 0.f;
    __syncthreads();
    for (int s = 0; s < CHL; ++s) {
        int t = t0 + s;
        float r3 = xb[(size_t)perm_idx(dir, t) * 256];
        float xc = cb + w0 * r0 + w1 * r1 + w2 * r2 + w3 * r3;
        r0 = r1; r1 = r2; r2 = r3;
        float xv = silu_fast(xc);
        const float* dr = dbs + s * RR;
        float da = dtb;
        #pragma unroll
        for (int r = 0; r < DTRN; ++r) da += pw[r] * dr[r];
        float dtv = softplus_fast(da);
        float u = dtv * xv;
        const float4* dq = (const float4*)(dr + DTRN);
        float4 B0 = dq[0], B1 = dq[1], B2 = dq[2], B3 = dq[3];
        float4 C0 = dq[4], C1 = dq[5], C2 = dq[6], C3 = dq[7];
        float y = 0.f;
        #define H_STEP(i, bv, cv) { float a = __expf(dtv * An[i]); h[i] = fmaf(h[i], a, u * (bv)); y = fmaf(h[i], (cv), y); }
        H_STEP(0, B0.x, C0.x) H_STEP(1, B0.y, C0.y) H_STEP(2, B0.z, C0.z) H_STEP(3, B0.w, C0.w)
        H_STEP(4, B1.x, C1.x) H_STEP(5, B1.y, C1.y) H_STEP(6, B1.z, C1.z) H_STEP(7, B1.w, C1.w)
        H_STEP(8, B2.x, C2.x) H_STEP(9, B2.y, C2.y) H_STEP(10, B2.z, C2.z) H_STEP(11, B2.w, C2.w)
        H_STEP(12, B3.x, C3.x) H_STEP(13, B3.y, C3.y) H_STEP(14, B3.z, C3.z) H_STEP(15, B3.w, C3.w)
        #undef H_STEP
        int lp = perm_idx(dir, t);
        atomicAdd(yb + (size_t)lp * 256, fmaf(Dd, xv, y));
    }
}

// ---------------------------------------------------------------------------
// K6: u[l][d] = ysum[l][d]*silu(z[l][d]); feat[fb][c][l] = sum_d Wout[c][d]*u
// Tiled: block = 32 l x 128 c, K=256 in 4 chunks of 64; microtile 2l x 8c.
__global__ __launch_bounds__(256) void k6_outproj(
    const float* __restrict__ ysum, const float* __restrict__ z_t,
    const float* __restrict__ Wout, float* __restrict__ feat)
{
    __shared__ float Ws[64 * 132];   // [dd][c]
    __shared__ float us[64 * 34];    // [dd][l]
    __shared__ float ft[128 * 34];   // output staging [c][l]
    int bid = blockIdx.x;
    int lt = bid & 127; int fb = bid >> 7;
    int l0 = lt * 32;
    int tid = threadIdx.x;
    int tx = tid & 15, ty = tid >> 4;   // c = tx*8.., l = ty*2..
    float acc[2][8];
    #pragma unroll
    for (int i = 0; i < 2; ++i)
        #pragma unroll
        for (int j = 0; j < 8; ++j) acc[i][j] = 0.f;
    for (int kt = 0; kt < 4; ++kt) {
        int dd0 = kt * 64;
        __syncthreads();
        // load Wout tile transposed: Ws[dd][c]
        for (int idx = tid; idx < 2048; idx += 256) {
            int c = idx >> 4, qq = idx & 15;
            float4 v = *(const float4*)&Wout[(size_t)c * 256 + dd0 + qq * 4];
            Ws[(qq * 4 + 0) * 132 + c] = v.x;
            Ws[(qq * 4 + 1) * 132 + c] = v.y;
            Ws[(qq * 4 + 2) * 132 + c] = v.z;
            Ws[(qq * 4 + 3) * 132 + c] = v.w;
        }
        // load u tile transposed: us[dd][l]
        for (int idx = tid; idx < 512; idx += 256) {
            int l = idx >> 4, qq = idx & 15;
            size_t gi = ((size_t)fb * LL + l0 + l) * 256 + dd0 + qq * 4;
            float4 yv = *(const float4*)&ysum[gi];
            float4 zv = *(const float4*)&z_t[gi];
            us[(qq * 4 + 0) * 34 + l] = yv.x * silu_fast(zv.x);
            us[(qq * 4 + 1) * 34 + l] = yv.y * silu_fast(zv.y);
            us[(qq * 4 + 2) * 34 + l] = yv.z * silu_fast(zv.z);
            us[(qq * 4 + 3) * 34 + l] = yv.w * silu_fast(zv.w);
        }
        __syncthreads();
        for (int k = 0; k < 64; ++k) {
            float2 uv = *(const float2*)&us[k * 34 + ty * 2];
            float4 w0 = *(const float4*)&Ws[k * 132 + tx * 8];
            float4 w1 = *(const float4*)&Ws[k * 132 + tx * 8 + 4];
            acc[0][0] = fmaf(uv.x, w0.x, acc[0][0]); acc[0][1] = fmaf(uv.x, w0.y, acc[0][1]);
            acc[0][2] = fmaf(uv.x, w0.z, acc[0][2]); acc[0][3] = fmaf(uv.x, w0.w, acc[0][3]);
            acc[0][4] = fmaf(uv.x, w1.x, acc[0][4]); acc[0][5] = fmaf(uv.x, w1.y, acc[0][5]);
            acc[0][6] = fmaf(uv.x, w1.z, acc[0][6]); acc[0][7] = fmaf(uv.x, w1.w, acc[0][7]);
            acc[1][0] = fmaf(uv.y, w0.x, acc[1][0]); acc[1][1] = fmaf(uv.y, w0.y, acc[1][1]);
            acc[1][2] = fmaf(uv.y, w0.z, acc[1][2]); acc[1][3] = fmaf(uv.y, w0.w, acc[1][3]);
            acc[1][4] = fmaf(uv.y, w1.x, acc[1][4]); acc[1][5] = fmaf(uv.y, w1.y, acc[1][5]);
            acc[1][6] = fmaf(uv.y, w1.z, acc[1][6]); acc[1][7] = fmaf(uv.y, w1.w, acc[1][7]);
        }
    }
    // stage output through LDS for coalesced [c][l] stores
    __syncthreads();
    #pragma unroll
    for (int i = 0; i < 2; ++i)
        #pragma unroll
        for (int j = 0; j < 8; ++j)
            ft[(tx * 8 + j) * 34 + ty * 2 + i] = acc[i][j];
    __syncthreads();
    for (int idx = tid; idx < 4096; idx += 256) {
        int c = idx >> 5, l = idx & 31;
        feat[((size_t)fb * 128 + c) * LL + l0 + l] = ft[c * 34 + l];
    }
}

// ---------------------------------------------------------------------------
// K7a: dp partials: partial[lc][b][c][d] = sum_{l in chunk} fA[c][l]*fB[d][l]
// 64x64 output tile, 4x4 microtile, K=128 per block in 2 LDS tiles of 64.
__global__ __launch_bounds__(256) void k7a_dp(
    const float* __restrict__ feat, float* __restrict__ partial)
{
    __shared__ float As[64 * 68];
    __shared__ float Bs[64 * 68];
    int bid = blockIdx.x;
    int lc = bid & 31; int dg = (bid >> 5) & 1; int cg = (bid >> 6) & 1; int b = (bid >> 7) & 1;
    int c0 = cg * 64, d0 = dg * 64, l0 = lc * 128;
    int tid = threadIdx.x;
    int tx = tid & 15, ty = tid >> 4;
    const float* fa = feat + (size_t)b * 128 * LL;
    const float* fbp = feat + (size_t)(2 + b) * 128 * LL;
    float acc[4][4];
    #pragma unroll
    for (int i = 0; i < 4; ++i)
        #pragma unroll
        for (int j = 0; j < 4; ++j) acc[i][j] = 0.f;
    for (int kt = 0; kt < 2; ++kt) {
        __syncthreads();
        for (int idx = tid; idx < 4096; idx += 256) {
            int r = idx >> 6, kk = idx & 63;
            As[kk * 68 + r] = fa[(size_t)(c0 + r) * LL + l0 + kt * 64 + kk];
            Bs[kk * 68 + r] = fbp[(size_t)(d0 + r) * LL + l0 + kt * 64 + kk];
        }
        __syncthreads();
        for (int k = 0; k < 64; ++k) {
            float4 av = *(const float4*)&As[k * 68 + ty * 4];
            float4 bv = *(const float4*)&Bs[k * 68 + tx * 4];
            acc[0][0] = fmaf(av.x, bv.x, acc[0][0]); acc[0][1] = fmaf(av.x, bv.y, acc[0][1]);
            acc[0][2] = fmaf(av.x, bv.z, acc[0][2]); acc[0][3] = fmaf(av.x, bv.w, acc[0][3]);
            acc[1][0] = fmaf(av.y, bv.x, acc[1][0]); acc[1][1] = fmaf(av.y, bv.y, acc[1][1]);
            acc[1][2] = fmaf(av.y, bv.z, acc[1][2]); acc[1][3] = fmaf(av.y, bv.w, acc[1][3]);
            acc[2][0] = fmaf(av.z, bv.x, acc[2][0]); acc[2][1] = fmaf(av.z, bv.y, acc[2][1]);
            acc[2][2] = fmaf(av.z, bv.z, acc[2][2]); acc[2][3] = fmaf(av.z, bv.w, acc[2][3]);
            acc[3][0] = fmaf(av.w, bv.x, acc[3][0]); acc[3][1] = fmaf(av.w, bv.y, acc[3][1]);
            acc[3][2] = fmaf(av.w, bv.z, acc[3][2]); acc[3][3] = fmaf(av.w, bv.w, acc[3][3]);
        }
    }
    float* pout = partial + (size_t)lc * 32768;
    #pragma unroll
    for (int i = 0; i < 4; ++i) {
        int c = c0 + ty * 4 + i;
        float4 v = make_float4(acc[i][0], acc[i][1], acc[i][2], acc[i][3]);
        *(float4*)&pout[((size_t)b * 128 + c) * 128 + d0 + tx * 4] = v;
    }
}

// K7a2: reduce 32 chunk partials -> dp
__global__ __launch_bounds__(256) void k7a2_reduce(
    const float* __restrict__ partial, float* __restrict__ dp)
{
    int id = blockIdx.x * 256 + threadIdx.x;   // 32768
    float s = 0.f;
    for (int ch = 0; ch < 32; ++ch) s += partial[(size_t)ch * 32768 + id];
    dp[id] = s;
}

// ---------------------------------------------------------------------------
// K7b: res_t[b][l][c] = sum_d dp[b][c][d]*featB[b][d][l]; + BN channel stats
// block = 32 l x 64 c; dp tile + featB tile fully in LDS; microtile 2l x 4c.
__global__ __launch_bounds__(256) void k7b_res(
    const float* __restrict__ feat, const float* __restrict__ dp,
    float* __restrict__ res_t, float* __restrict__ stats)
{
    __shared__ float Bs[128 * 34];   // [d][l]
    __shared__ float Ds[128 * 68];   // [d][c]
    __shared__ float red[256];
    int bid = blockIdx.x;
    int lt = bid & 127; int cg = (bid >> 7) & 1; int b = bid >> 8;
    int l0 = lt * 32, c0 = cg * 64;
    int tid = threadIdx.x;
    const float* fbp = feat + (size_t)(2 + b) * 128 * LL;
    for (int idx = tid; idx < 4096; idx += 256) {
        int d = idx >> 5, l = idx & 31;
        Bs[d * 34 + l] = fbp[(size_t)d * LL + l0 + l];
    }
    for (int idx = tid; idx < 8192; idx += 256) {
        int c = idx >> 7, d = idx & 127;
        Ds[d * 68 + c] = dp[((size_t)b * 128 + c0 + c) * 128 + d];
    }
    __syncthreads();
    int tx = tid & 15, ty = tid >> 4;   // c = c0+tx*4, l = l0+ty*2
    float acc[2][4];
    #pragma unroll
    for (int i = 0; i < 2; ++i)
        #pragma unroll
        for (int j = 0; j < 4; ++j) acc[i][j] = 0.f;
    for (int d = 0; d < 128; ++d) {
        float2 bv = *(const float2*)&Bs[d * 34 + ty * 2];
        float4 dv = *(const float4*)&Ds[d * 68 + tx * 4];
        acc[0][0] = fmaf(bv.x, dv.x, acc[0][0]); acc[0][1] = fmaf(bv.x, dv.y, acc[0][1]);
        acc[0][2] = fmaf(bv.x, dv.z, acc[0][2]); acc[0][3] = fmaf(bv.x, dv.w, acc[0][3]);
        acc[1][0] = fmaf(bv.y, dv.x, acc[1][0]); acc[1][1] = fmaf(bv.y, dv.y, acc[1][1]);
        acc[1][2] = fmaf(bv.y, dv.z, acc[1][2]); acc[1][3] = fmaf(bv.y, dv.w, acc[1][3]);
    }
    float s1 = 0.f, s2 = 0.f;
    #pragma unroll
    for (int i = 0; i < 2; ++i) {
        size_t l = (size_t)(l0 + ty * 2 + i);
        float4 v = make_float4(acc[i][0], acc[i][1], acc[i][2], acc[i][3]);
        *(float4*)&res_t[((size_t)b * LL + l) * 128 + c0 + tx * 4] = v;
        s1 += acc[i][0] + acc[i][1] + acc[i][2] + acc[i][3];
        s2 += acc[i][0]*acc[i][0] + acc[i][1]*acc[i][1] + acc[i][2]*acc[i][2] + acc[i][3]*acc[i][3];
    }
    red[tid] = s1; __syncthreads();
    for (int s = 128; s > 0; s >>= 1) { if (tid < s) red[tid] += red[tid + s]; __syncthreads(); }
    if (tid == 0) atomicAdd(&stats[lt], red[0]);
    __syncthreads();
    red[tid] = s2; __syncthreads();
    for (int s = 128; s > 0; s >>= 1) { if (tid < s) red[tid] += red[tid + s]; __syncthreads(); }
    if (tid == 0) atomicAdd(&stats[128 + lt], red[0]);
}

// ---------------------------------------------------------------------------
// K7d: batchnorm finalize; res_t flat index == output flat index
__global__ __launch_bounds__(256) void k7d_bn(
    const float* __restrict__ res_t, const float* __restrict__ stats,
    const float* __restrict__ bn_g, const float* __restrict__ bn_b,
    float* __restrict__ outp)
{
    int i = blockIdx.x * 256 + threadIdx.x;   // 1048576 total
    int m = i & (524288 - 1);
    int cp = m >> 12;
    float mu = stats[cp] * (1.0f / 8192.0f);
    float var = stats[128 + cp] * (1.0f / 8192.0f) - mu * mu;
    float v = res_t[i];
    outp[i] = (v - mu) * rsqrtf(var + EPSF) * bn_g[cp] + bn_b[cp];
}

// ---------------------------------------------------------------------------
extern "C" void kernel_launch(void* const* d_in, const int* in_sizes, int n_in,
                              void* d_out, int out_size, void* d_ws, size_t ws_size,
                              hipStream_t stream)
{
    (void)in_sizes; (void)n_in; (void)out_size; (void)ws_size;
    const float* x1   = (const float*)d_in[0];
    const float* x2   = (const float*)d_in[1];
    const float* ln_g = (const float*)d_in[2];
    const float* ln_b = (const float*)d_in[3];
    const float* Win  = (const float*)d_in[4];
    const float* cw   = (const float*)d_in[5];
    const float* cb   = (const float*)d_in[6];
    const float* xpw  = (const float*)d_in[7];
    const float* dpw  = (const float*)d_in[8];
    const float* dpb  = (const float*)d_in[9];
    const float* Alog = (const float*)d_in[10];
    const float* Dv   = (const float*)d_in[11];
    const float* Wout = (const float*)d_in[12];
    const float* bn_g = (const float*)d_in[13];
    const float* bn_b = (const float*)d_in[14];
    float* outp = (float*)d_out;
    float* ws = (float*)d_ws;

    float* x_t  = ws + O_XT;
    float* z_t  = ws + O_ZT;
    float* xn   = ws + O_XN;
    float* dblt = ws + O_DBL;
    float* Pb   = ws + O_P;
    float* Sb   = ws + O_S;
    float* Hb   = ws + O_H;
    float* ysum = ws + O_YS;
    float* feat = ws + O_FT;
    float* dpB  = ws + O_DP;
    float* rest = ws + O_RT;
    float* stat = ws + O_ST;
    float* part = ws + O_PART;

    hipMemsetAsync(ysum, 0, (size_t)4194304 * 4, stream);
    hipMemsetAsync(stat, 0, (size_t)256 * 4, stream);

    k0_ln<<<256, 256, 0, stream>>>(x1, x2, ln_g, ln_b, xn);
    k1_gemm<<<2048, 256, 0, stream>>>(xn, Win, x_t, z_t);
    k2_conv_xproj<<<1536, 256, 0, stream>>>(x_t, cw, cb, xpw, dblt);
    k3_pass1<<<768, 256, 0, stream>>>(x_t, dblt, cw, cb, dpw, dpb, Alog, Pb, Sb);
    k4_combine<<<192, 256, 0, stream>>>(Pb, Sb, Hb);
    k5_pass3<<<768, 256, 0, stream>>>(x_t, dblt, cw, cb, dpw, dpb, Alog, Dv, Hb, ysum);
    k6_outproj<<<512, 256, 0, stream>>>(ysum, z_t, Wout, feat);
    k7a_dp<<<256, 256, 0, stream>>>(feat, part);
    k7a2_reduce<<<128, 256, 0, stream>>>(part, dpB);
    k7b_res<<<512, 256, 0, stream>>>(feat, dpB, rest, stat);
    k7d_bn<<<4096, 256, 0, stream>>>(rest, stat, bn_g, bn_b, outp);
}